// Round 7
// baseline (439.099 us; speedup 1.0000x reference)
//
#include <hip/hip_runtime.h>
#include <math.h>

#define HID 128
#define G3  384
#define BATCH 256
#define SEQ 512
#define NB 16            // batch tile per block
#define NBLK (BATCH/NB)  // 16 blocks

typedef __bf16 bf16x8 __attribute__((ext_vector_type(8)));
typedef __bf16 bf16x4 __attribute__((ext_vector_type(4)));
typedef float  f32x4  __attribute__((ext_vector_type(4)));

#define LOG2E 1.44269504088896f

__device__ __forceinline__ float sigm(float x) {
    return __builtin_amdgcn_rcpf(1.f + __builtin_amdgcn_exp2f(-LOG2E * x));
}
__device__ __forceinline__ float tanh_fast(float x) {
    float e = __builtin_amdgcn_exp2f(-2.f * LOG2E * x);
    return __builtin_amdgcn_rcpf(1.f + e) * 2.f - 1.f;
}
__device__ __forceinline__ f32x4 mfma16(bf16x8 a, bf16x8 b, f32x4 c) {
    return __builtin_amdgcn_mfma_f32_16x16x32_bf16(a, b, c, 0, 0, 0);
}
__device__ __forceinline__ bf16x8 cvt8(float4 a, float4 b) {
    bf16x8 f;
    f[0] = (__bf16)a.x; f[1] = (__bf16)a.y; f[2] = (__bf16)a.z; f[3] = (__bf16)a.w;
    f[4] = (__bf16)b.x; f[5] = (__bf16)b.y; f[6] = (__bf16)b.z; f[7] = (__bf16)b.w;
    return f;
}
__device__ __forceinline__ bf16x4 cvt4(float4 a) {
    bf16x4 f;
    f[0] = (__bf16)a.x; f[1] = (__bf16)a.y; f[2] = (__bf16)a.z; f[3] = (__bf16)a.w;
    return f;
}

// ---------------------------------------------------------------------------
// Kernel 1: fold Linear into GRU input-hidden weights (unchanged).
// ---------------------------------------------------------------------------
__global__ void fold_kernel(const float* __restrict__ lin_W,
                            const float* __restrict__ lin_b,
                            const float* __restrict__ W_ih,
                            const float* __restrict__ b_ih,
                            float* __restrict__ Wc,
                            float* __restrict__ bcA) {
    const int g = blockIdx.x;
    const int d = threadIdx.x;
    float acc = 0.f;
    for (int e = 0; e < HID; ++e) acc += W_ih[g * HID + e] * lin_W[e * HID + d];
    Wc[g * HID + d] = acc;
    if (d == 0) {
        float b = 0.f;
        for (int e = 0; e < HID; ++e) b += W_ih[g * HID + e] * lin_b[e];
        bcA[g] = b + b_ih[g];
    }
}

// ---------------------------------------------------------------------------
// Kernel 2: MFMA GRU scan. Round-6 structure (8 waves / 512 thr, weights
// resident as bf16 A-frags, XOR-swizzled LDS) with ONE barrier per step:
// h AND x double-buffered, so between consecutive barriers every wave only
// reads {hR,xR} and writes {hW,xW} -- disjoint -> one s_barrier suffices.
// Barrier drains lgkmcnt only; NO vmcnt wait exists in the loop: out-stores
// and the x[s+2] prefetch stay in flight across barriers. The prefetch is
// consumed (bf16-converted + staged) at the TOP of the NEXT step, ~2000 cy
// after issue, so its implicit vmcnt wait is free (round-5's same-step pin
// was the bug there). Gate biases folded into MFMA accumulator init.
// ---------------------------------------------------------------------------
__global__ __launch_bounds__(512, 2)
void gru_scan_mfma(const float* __restrict__ X,
                   const float* __restrict__ h0,
                   const float* __restrict__ W_hh,
                   const float* __restrict__ b_hh,
                   const float* __restrict__ Wc,
                   const float* __restrict__ bcA,
                   float* __restrict__ out) {
    const int t   = threadIdx.x;
    const int w   = t >> 6;     // 0..7: row tile (16 rows of each gate)
    const int l   = t & 63;
    const int col = l & 15;     // batch within tile (MFMA n / C col)
    const int lr  = l >> 4;     // 0..3
    const int bb  = blockIdx.x * NB;

    __shared__ __align__(16) unsigned char lds[16384];
    unsigned char* hA = lds;            // h buffer, even-step read
    unsigned char* hB = lds + 4096;     // h buffer, odd-step read
    unsigned char* xA = lds + 8192;     // x buffer, even-step read
    unsigned char* xB = lds + 12288;    // x buffer, odd-step read

    auto SW = [](int b, int off) { return b * 256 + (off ^ ((b & 7) << 4)); };

    // ---- resident A-fragments: aW = W_hh, aC = Wc; [gate][ktile] --------
    bf16x8 aW[3][4], aC[3][4];
    #pragma unroll
    for (int g3 = 0; g3 < 3; ++g3)
        #pragma unroll
        for (int kt = 0; kt < 4; ++kt) {
            const int row = g3 * HID + w * 16 + col;
            const float* pw = W_hh + row * HID + kt * 32 + lr * 8;
            const float* pc = Wc   + row * HID + kt * 32 + lr * 8;
            aW[g3][kt] = cvt8(*(const float4*)pw, *(const float4*)(pw + 4));
            aC[g3][kt] = cvt8(*(const float4*)pc, *(const float4*)(pc + 4));
        }
    #pragma unroll
    for (int g3 = 0; g3 < 3; ++g3)
        #pragma unroll
        for (int kt = 0; kt < 4; ++kt) {
            asm volatile("" : "+v"(aW[g3][kt]));
            asm volatile("" : "+v"(aC[g3][kt]));
        }

    // ---- biases as f32x4 acc initializers (g = w*16 + lr*4 + q) ---------
    f32x4 vbr, vbz, vbnx, vbnh;
    #pragma unroll
    for (int q = 0; q < 4; ++q) {
        const int g = w * 16 + lr * 4 + q;
        vbr[q]  = bcA[g] + b_hh[g];
        vbz[q]  = bcA[HID + g] + b_hh[HID + g];
        vbnx[q] = bcA[2 * HID + g];
        vbnh[q] = b_hh[2 * HID + g];
    }

    // ---- h_old rows this lane owns (fp32, registers) --------------------
    f32x4 hold = *(const f32x4*)(h0 + (size_t)(bb + col) * HID + w * 16 + lr * 4);

    // ---- staging mapping: all 512 threads, 16B global read / 8B LDS write
    const int sb = t >> 5;            // 0..15 batch row
    const int sk = (t & 31) * 4;      // 0..124 k offset (floats)

    // ---- prime: h0 -> hA, x[0] -> xA, x[1] -> regs ----------------------
    float4 xp, xq;                    // ping-pong prefetch regs
    if (t < 256) {
        const int hb = t >> 4, hk = (t & 15) * 8;
        const float* ph = h0 + (size_t)(bb + hb) * HID + hk;
        *(bf16x8*)(hA + SW(hb, hk * 2)) =
            cvt8(*(const float4*)ph, *(const float4*)(ph + 4));
    }
    {
        const float* px = X + ((size_t)0 * BATCH + bb + sb) * HID + sk;
        *(bf16x4*)(xA + SW(sb, sk * 2)) = cvt4(*(const float4*)px);
        const float* p1 = X + ((size_t)1 * BATCH + bb + sb) * HID + sk;
        xp = *(const float4*)p1;
    }
    asm volatile("s_waitcnt lgkmcnt(0)" ::: "memory");
    __builtin_amdgcn_s_barrier();

    auto STEP = [&](int s, unsigned char* hR, unsigned char* hW,
                    unsigned char* xR, unsigned char* xW,
                    float4& xc, float4& xn) {
        // 1. stage x[s+1] (regs loaded a full step ago -> vmcnt wait free)
        *(bf16x4*)(xW + SW(sb, sk * 2)) = cvt4(xc);

        // 2. issue x[s+2] prefetch (consumed top of step s+2; never waited
        //    on in this step -- no vmcnt drain exists below)
        {
            int sp = s + 2; if (sp > SEQ - 1) sp = SEQ - 1;
            const float* px = X + ((size_t)sp * BATCH + bb + sb) * HID + sk;
            xn = *(const float4*)px;
        }

        // 3. B-fragments from LDS
        bf16x8 Bh[4], Bx[4];
        #pragma unroll
        for (int kt = 0; kt < 4; ++kt) {
            Bh[kt] = *(const bf16x8*)(hR + SW(col, kt * 64 + lr * 16));
            Bx[kt] = *(const bf16x8*)(xR + SW(col, kt * 64 + lr * 16));
        }

        // 4. MFMA: 24 per wave, accumulators init'd with gate biases
        f32x4 ar = vbr, az = vbz, anh = vbnh, anx = vbnx;
        #pragma unroll
        for (int kt = 0; kt < 4; ++kt) {
            ar  = mfma16(aW[0][kt], Bh[kt], ar);
            ar  = mfma16(aC[0][kt], Bx[kt], ar);
            az  = mfma16(aW[1][kt], Bh[kt], az);
            az  = mfma16(aC[1][kt], Bx[kt], az);
            anh = mfma16(aW[2][kt], Bh[kt], anh);
            anx = mfma16(aC[2][kt], Bx[kt], anx);
        }

        // 5. gate math (fp32, registers) + h_new writeback
        f32x4 hnew;
        #pragma unroll
        for (int q = 0; q < 4; ++q) {
            float r = sigm(ar[q]);
            float z = sigm(az[q]);
            float n = tanh_fast(anx[q] + r * anh[q]);
            hnew[q] = n + z * (hold[q] - n);
        }
        hold = hnew;
        *(bf16x4*)(hW + SW(col, (w * 16 + lr * 4) * 2)) = cvt4(*(float4*)&hnew);
        float4 o; o.x = hnew[0]; o.y = hnew[1]; o.z = hnew[2]; o.w = hnew[3];
        *(float4*)(out + ((size_t)s * BATCH + bb + col) * HID + w * 16 + lr * 4) = o;

        // 6. single barrier: LDS visibility only; vmcnt flows across.
        asm volatile("s_waitcnt lgkmcnt(0)" ::: "memory");
        __builtin_amdgcn_s_barrier();
    };

    for (int s0 = 0; s0 < SEQ; s0 += 2) {
        STEP(s0,     hA, hB, xA, xB, xp, xq);
        STEP(s0 + 1, hB, hA, xB, xA, xq, xp);
    }
}

// ---------------------------------------------------------------------------
extern "C" void kernel_launch(void* const* d_in, const int* in_sizes, int n_in,
                              void* d_out, int out_size, void* d_ws, size_t ws_size,
                              hipStream_t stream) {
    const float* X     = (const float*)d_in[0];
    const float* h0    = (const float*)d_in[1];
    const float* lin_W = (const float*)d_in[2];
    const float* lin_b = (const float*)d_in[3];
    const float* W_ih  = (const float*)d_in[4];
    const float* W_hh  = (const float*)d_in[5];
    const float* b_ih  = (const float*)d_in[6];
    const float* b_hh  = (const float*)d_in[7];
    float* out = (float*)d_out;

    float* Wc  = (float*)d_ws;
    float* bcA = Wc + G3 * HID;

    fold_kernel<<<G3, HID, 0, stream>>>(lin_W, lin_b, W_ih, b_ih, Wc, bcA);
    gru_scan_mfma<<<NBLK, 512, 0, stream>>>(X, h0, W_hh, b_hh, Wc, bcA, out);
}